// Round 6
// baseline (182.579 us; speedup 1.0000x reference)
//
#include <hip/hip_runtime.h>

// (B,H,W,C) = (16,512,512,3) float32. 4 warp ops.
// out concat order: 0:(frame1,f01) 1:(frame0,f10) 2:(frame0,ft0) 3:(frame1,ft1)
#define HH 512
#define WW 512
#define NPIX (16 * HH * WW)
#define ROWD_G (WW * 3)          // global image row stride in dwords

#define TS    32                 // output tile edge
#define APR   12                 // apron
#define LW    (TS + 2 * APR)     // 56
#define ROWD  (LW * 3)           // 168 payload dwords per region row
#define LSTR  172                // padded LDS row stride (16B-aligned)
#define NDW   (LW * ROWD)        // 9408 staged dwords

typedef float fv4 __attribute__((ext_vector_type(4)));
typedef float fv2 __attribute__((ext_vector_type(2)));
typedef fv4 fv4u __attribute__((aligned(4)));
typedef fv2 fv2u __attribute__((aligned(4)));

// Load one tile's 56x56 apron region into 10 fv4 registers (global-linear order).
__device__ __forceinline__ void load_stage(const float* __restrict__ imgb,
                                           int AX0, int AY0, int tid, fv4* st)
{
    const bool interior = (AX0 >= 0) && (AX0 + LW <= WW);  // wave-uniform
#pragma unroll
    for (int k = 0; k < 10; ++k) {
        const int d = tid * 4 + k * 1024;
        if (d < NDW) {
            const int row = d / ROWD;
            const int rd  = d - row * ROWD;
            const int gy  = min(max(AY0 + row, 0), HH - 1);
            const float* rowp = imgb + (size_t)gy * ROWD_G;
            if (interior) {
                st[k] = *(const fv4u*)(rowp + AX0 * 3 + rd);
            } else {
                const int p0 = rd / 3;
                if (AX0 + p0 >= 0 && AX0 + p0 + 1 <= WW - 1) {
                    st[k] = *(const fv4u*)(rowp + AX0 * 3 + rd);
                } else {
                    fv4 vals;
#pragma unroll
                    for (int j = 0; j < 4; ++j) {
                        const int e  = rd + j;
                        const int pe = e / 3;
                        const int ce = e - pe * 3;
                        const int gx = min(max(AX0 + pe, 0), WW - 1);
                        vals[j] = rowp[gx * 3 + ce];
                    }
                    st[k] = vals;
                }
            }
        }
    }
}

__device__ __forceinline__ void sample(const float* __restrict__ imgb,
                                       const float* __restrict__ s,
                                       int AX0, int AY0,
                                       float qy, float qx, float* __restrict__ r)
{
    float fy = floorf(qy); fy = fminf(fmaxf(fy, 0.0f), (float)(HH - 2));
    float fx = floorf(qx); fx = fminf(fmaxf(fx, 0.0f), (float)(WW - 2));
    const float ay = fminf(fmaxf(qy - fy, 0.0f), 1.0f);
    const float ax = fminf(fmaxf(qx - fx, 0.0f), 1.0f);
    const int y0 = (int)fy, x0 = (int)fx;
    const int yl = y0 - AY0, xl = x0 - AX0;
    if ((unsigned)yl < (unsigned)(LW - 1) && (unsigned)xl < (unsigned)(LW - 1)) {
        // LDS path: AoS rows; adjacent-pair dwords -> ds_read2_b32
        const float* t  = s + yl * LSTR + 3 * xl;
        const float* bo = t + LSTR;
#pragma unroll
        for (int c = 0; c < 3; ++c) {
            const float tl = t[c],  tr = t[c + 3];
            const float bl = bo[c], br = bo[c + 3];
            const float top = tl + ax * (tr - tl);
            const float bot = bl + ax * (br - bl);
            r[c] = top + ay * (bot - top);
        }
    } else {
        // rare global fallback (|flow| beyond apron): exact same math
        const float* t  = imgb + ((size_t)y0 * WW + x0) * 3;
        const float* bo = t + WW * 3;
        const fv4u t4 = *(const fv4u*)t;  const fv2u t2 = *(const fv2u*)(t + 4);
        const fv4u b4 = *(const fv4u*)bo; const fv2u b2 = *(const fv2u*)(bo + 4);
        const float tv[6] = {t4.x, t4.y, t4.z, t4.w, t2.x, t2.y};
        const float bv[6] = {b4.x, b4.y, b4.z, b4.w, b2.x, b2.y};
#pragma unroll
        for (int c = 0; c < 3; ++c) {
            const float top = tv[c] + ax * (tv[c + 3] - tv[c]);
            const float bot = bv[c] + ax * (bv[c + 3] - bv[c]);
            r[c] = top + ay * (bot - top);
        }
    }
}

// 2048 blocks; each block pipelines 4 x-adjacent tiles of one (fg,b) image.
__global__ __launch_bounds__(256, 4) void warp_pipe_kernel(
    const float* __restrict__ frame0, const float* __restrict__ frame1,
    const float* __restrict__ f01, const float* __restrict__ f10,
    const float* __restrict__ ft0, const float* __restrict__ ft1,
    float* __restrict__ out)
{
    __shared__ float lds[LW * LSTR];   // 38,528 B -> 4 blocks/CU

    // Bijective XCD chunking over 2048 block-units (each = 4 tiles):
    // XCD k gets 256 contiguous units = 4 whole images (3 MB fits 4 MB L2).
    const unsigned bid = blockIdx.x;
    const unsigned u   = (bid & 7u) * 256u + (bid >> 3);
    const unsigned v0  = u * 4u;             // first tile id; tiles v0..v0+3

    const unsigned img_b = v0 >> 8;          // constant across the 4 tiles
    const int b  = (int)(img_b & 15u);
    const int fg = (int)(img_b >> 4);        // 0: frame0 ops{1,2}, 1: frame1 ops{0,3}
    const int txb = (int)(v0 & 15u);         // 0,4,8,12
    const int ty  = (int)((v0 >> 4) & 15u);

    const float* img   = fg ? frame1 : frame0;
    const float* flowA = fg ? f01 : f10;
    const float* flowB = fg ? ft1 : ft0;
    const size_t opA   = fg ? 0 : 1;
    const size_t opB   = fg ? 3 : 2;
    const float* imgb  = img + (size_t)b * (HH * WW * 3);

    const int tid = (int)threadIdx.x;
    const int lx = (tid & 7) * 4;            // 8 threads x 4 px per 32-px row
    const int ly = tid >> 3;                 // 32 rows
    const int Y0 = ty * TS;
    const int y  = Y0 + ly;
    const int AY0 = Y0 - APR;
    const size_t rowBase = ((size_t)b * HH + y) * WW;

    fv4 st[10];
    fv4 fA0, fA1, fB0, fB1;

    // Prologue: prefetch tile 0 (apron -> regs, flows -> regs).
    {
        const int AX0 = txb * TS - APR;
        load_stage(imgb, AX0, AY0, tid, st);
        const size_t pixIn = rowBase + txb * TS + lx;
        fA0 = __builtin_nontemporal_load((const fv4*)(flowA + pixIn * 2));
        fA1 = __builtin_nontemporal_load((const fv4*)(flowA + pixIn * 2) + 1);
        fB0 = __builtin_nontemporal_load((const fv4*)(flowB + pixIn * 2));
        fB1 = __builtin_nontemporal_load((const fv4*)(flowB + pixIn * 2) + 1);
    }

#pragma unroll
    for (int i = 0; i < 4; ++i) {
        const int X0  = (txb + i) * TS;
        const int AX0 = X0 - APR;
        const int x   = X0 + lx;
        const size_t pixIn = rowBase + x;

        __syncthreads();                     // prev compute done; LDS reusable
        // Commit staged regs -> LDS (ds_write_b128, conflict-free).
#pragma unroll
        for (int k = 0; k < 10; ++k) {
            const int d = tid * 4 + k * 1024;
            if (d < NDW) {
                const int row = d / ROWD;
                const int rd  = d - row * ROWD;
                *(fv4*)(lds + row * LSTR + rd) = st[k];
            }
        }
        const fv4 a0 = fA0, a1 = fA1, c0 = fB0, c1 = fB1;  // current flows
        __syncthreads();

        // Prefetch next tile; latency hides under compute+stores below.
        if (i < 3) {
            load_stage(imgb, AX0 + TS, AY0, tid, st);
            const size_t pixInN = pixIn + TS;
            fA0 = __builtin_nontemporal_load((const fv4*)(flowA + pixInN * 2));
            fA1 = __builtin_nontemporal_load((const fv4*)(flowA + pixInN * 2) + 1);
            fB0 = __builtin_nontemporal_load((const fv4*)(flowB + pixInN * 2));
            fB1 = __builtin_nontemporal_load((const fv4*)(flowB + pixInN * 2) + 1);
        }

        const float flyA[4] = {a0.x, a0.z, a1.x, a1.z};
        const float flxA[4] = {a0.y, a0.w, a1.y, a1.w};
        const float flyB[4] = {c0.x, c0.z, c1.x, c1.z};
        const float flxB[4] = {c0.y, c0.w, c1.y, c1.w};

        float resA[12], resB[12];
#pragma unroll
        for (int p = 0; p < 4; ++p) {
            sample(imgb, lds, AX0, AY0, (float)y - flyA[p], (float)(x + p) - flxA[p], resA + 3 * p);
            sample(imgb, lds, AX0, AY0, (float)y - flyB[p], (float)(x + p) - flxB[p], resB + 3 * p);
        }

        float* oA = out + (opA * NPIX + pixIn) * 3;
        float* oB = out + (opB * NPIX + pixIn) * 3;
        fv4 vA0 = {resA[0], resA[1], resA[2],  resA[3]};
        fv4 vA1 = {resA[4], resA[5], resA[6],  resA[7]};
        fv4 vA2 = {resA[8], resA[9], resA[10], resA[11]};
        fv4 vB0 = {resB[0], resB[1], resB[2],  resB[3]};
        fv4 vB1 = {resB[4], resB[5], resB[6],  resB[7]};
        fv4 vB2 = {resB[8], resB[9], resB[10], resB[11]};
        __builtin_nontemporal_store(vA0, (fv4*)oA);
        __builtin_nontemporal_store(vA1, (fv4*)oA + 1);
        __builtin_nontemporal_store(vA2, (fv4*)oA + 2);
        __builtin_nontemporal_store(vB0, (fv4*)oB);
        __builtin_nontemporal_store(vB1, (fv4*)oB + 1);
        __builtin_nontemporal_store(vB2, (fv4*)oB + 2);
    }
}

extern "C" void kernel_launch(void* const* d_in, const int* in_sizes, int n_in,
                              void* d_out, int out_size, void* d_ws, size_t ws_size,
                              hipStream_t stream) {
    const float* frame0 = (const float*)d_in[0];
    const float* frame1 = (const float*)d_in[1];
    const float* f01    = (const float*)d_in[2];
    const float* f10    = (const float*)d_in[3];
    const float* ft0    = (const float*)d_in[4];
    const float* ft1    = (const float*)d_in[5];
    float* out = (float*)d_out;

    // 2 frame-groups * 16 b * 256 tiles / 4 tiles-per-block = 2048 blocks.
    hipLaunchKernelGGL(warp_pipe_kernel, dim3(2048), dim3(256), 0, stream,
                       frame0, frame1, f01, f10, ft0, ft1, out);
}

// Round 7
// 167.693 us; speedup vs baseline: 1.0888x; 1.0888x over previous
//
#include <hip/hip_runtime.h>

// (B,H,W,C) = (16,512,512,3) float32. 4 warp ops.
// out concat order: 0:(frame1,f01) 1:(frame0,f10) 2:(frame0,ft0) 3:(frame1,ft1)
#define HH 512
#define WW 512
#define NPIX (16 * HH * WW)
#define ROWD_G (WW * 3)          // global image row stride in dwords

#define TS    32                 // output tile edge
#define APR   12                 // apron
#define LW    (TS + 2 * APR)     // 56
#define ROWD  (LW * 3)           // 168 payload dwords per region row
#define LSTR  172                // padded LDS row stride (16B-aligned)
#define NDW   (LW * ROWD)        // 9408 staged dwords

typedef float fv4 __attribute__((ext_vector_type(4)));
typedef float fv2 __attribute__((ext_vector_type(2)));
typedef fv4 fv4u __attribute__((aligned(4)));
typedef fv2 fv2u __attribute__((aligned(4)));

// Load one tile's 56x56 apron region into 10 fv4 registers (global-linear order).
__device__ __forceinline__ void load_stage(const float* __restrict__ imgb,
                                           int AX0, int AY0, int tid, fv4* st)
{
    const bool interior = (AX0 >= 0) && (AX0 + LW <= WW);  // wave-uniform
#pragma unroll
    for (int k = 0; k < 10; ++k) {
        const int d = tid * 4 + k * 1024;
        if (d < NDW) {
            const int row = d / ROWD;
            const int rd  = d - row * ROWD;
            const int gy  = min(max(AY0 + row, 0), HH - 1);
            const float* rowp = imgb + (size_t)gy * ROWD_G;
            if (interior) {
                st[k] = *(const fv4u*)(rowp + AX0 * 3 + rd);
            } else {
                const int p0 = rd / 3;
                if (AX0 + p0 >= 0 && AX0 + p0 + 1 <= WW - 1) {
                    st[k] = *(const fv4u*)(rowp + AX0 * 3 + rd);
                } else {
                    fv4 vals;
#pragma unroll
                    for (int j = 0; j < 4; ++j) {
                        const int e  = rd + j;
                        const int pe = e / 3;
                        const int ce = e - pe * 3;
                        const int gx = min(max(AX0 + pe, 0), WW - 1);
                        vals[j] = rowp[gx * 3 + ce];
                    }
                    st[k] = vals;
                }
            }
        }
    }
}

__device__ __forceinline__ void sample(const float* __restrict__ imgb,
                                       const float* __restrict__ s,
                                       int AX0, int AY0,
                                       float qy, float qx, float* __restrict__ r)
{
    float fy = floorf(qy); fy = fminf(fmaxf(fy, 0.0f), (float)(HH - 2));
    float fx = floorf(qx); fx = fminf(fmaxf(fx, 0.0f), (float)(WW - 2));
    const float ay = fminf(fmaxf(qy - fy, 0.0f), 1.0f);
    const float ax = fminf(fmaxf(qx - fx, 0.0f), 1.0f);
    const int y0 = (int)fy, x0 = (int)fx;
    const int yl = y0 - AY0, xl = x0 - AX0;
    if ((unsigned)yl < (unsigned)(LW - 1) && (unsigned)xl < (unsigned)(LW - 1)) {
        // LDS path: AoS rows; adjacent-pair dwords -> ds_read2_b32
        const float* t  = s + yl * LSTR + 3 * xl;
        const float* bo = t + LSTR;
#pragma unroll
        for (int c = 0; c < 3; ++c) {
            const float tl = t[c],  tr = t[c + 3];
            const float bl = bo[c], br = bo[c + 3];
            const float top = tl + ax * (tr - tl);
            const float bot = bl + ax * (br - bl);
            r[c] = top + ay * (bot - top);
        }
    } else {
        // rare global fallback (|flow| beyond apron): exact same math
        const float* t  = imgb + ((size_t)y0 * WW + x0) * 3;
        const float* bo = t + WW * 3;
        const fv4u t4 = *(const fv4u*)t;  const fv2u t2 = *(const fv2u*)(t + 4);
        const fv4u b4 = *(const fv4u*)bo; const fv2u b2 = *(const fv2u*)(bo + 4);
        const float tv[6] = {t4.x, t4.y, t4.z, t4.w, t2.x, t2.y};
        const float bv[6] = {b4.x, b4.y, b4.z, b4.w, b2.x, b2.y};
#pragma unroll
        for (int c = 0; c < 3; ++c) {
            const float top = tv[c] + ax * (tv[c + 3] - tv[c]);
            const float bot = bv[c] + ax * (bv[c + 3] - bv[c]);
            r[c] = top + ay * (bot - top);
        }
    }
}

// 2048 blocks; each block pipelines 4 x-adjacent tiles of one (fg,b) image.
// LDS (38.5 KB) caps residency at 4 blocks/CU = 4 waves/SIMD, so pin exactly
// that and give the register allocator its full 128-VGPR budget (R6 spilled
// the st[] prefetch to scratch at VGPR=64: +-170 MB HBM round-trip).
__global__ __attribute__((amdgpu_flat_work_group_size(256, 256),
                          amdgpu_waves_per_eu(4, 4)))
void warp_pipe_kernel(
    const float* __restrict__ frame0, const float* __restrict__ frame1,
    const float* __restrict__ f01, const float* __restrict__ f10,
    const float* __restrict__ ft0, const float* __restrict__ ft1,
    float* __restrict__ out)
{
    __shared__ float lds[LW * LSTR];   // 38,528 B -> 4 blocks/CU

    // Bijective XCD chunking over 2048 block-units (each = 4 tiles):
    // XCD k gets 256 contiguous units = 4 whole images (3 MB fits 4 MB L2).
    const unsigned bid = blockIdx.x;
    const unsigned u   = (bid & 7u) * 256u + (bid >> 3);
    const unsigned v0  = u * 4u;             // first tile id; tiles v0..v0+3

    const unsigned img_b = v0 >> 8;          // constant across the 4 tiles
    const int b  = (int)(img_b & 15u);
    const int fg = (int)(img_b >> 4);        // 0: frame0 ops{1,2}, 1: frame1 ops{0,3}
    const int txb = (int)(v0 & 15u);         // 0,4,8,12
    const int ty  = (int)((v0 >> 4) & 15u);

    const float* img   = fg ? frame1 : frame0;
    const float* flowA = fg ? f01 : f10;
    const float* flowB = fg ? ft1 : ft0;
    const size_t opA   = fg ? 0 : 1;
    const size_t opB   = fg ? 3 : 2;
    const float* imgb  = img + (size_t)b * (HH * WW * 3);

    const int tid = (int)threadIdx.x;
    const int lx = (tid & 7) * 4;            // 8 threads x 4 px per 32-px row
    const int ly = tid >> 3;                 // 32 rows
    const int Y0 = ty * TS;
    const int y  = Y0 + ly;
    const int AY0 = Y0 - APR;
    const size_t rowBase = ((size_t)b * HH + y) * WW;

    fv4 st[10];
    fv4 fA0, fA1, fB0, fB1;

    // Prologue: prefetch tile 0 (apron -> regs, flows -> regs).
    {
        const int AX0 = txb * TS - APR;
        load_stage(imgb, AX0, AY0, tid, st);
        const size_t pixIn = rowBase + txb * TS + lx;
        fA0 = __builtin_nontemporal_load((const fv4*)(flowA + pixIn * 2));
        fA1 = __builtin_nontemporal_load((const fv4*)(flowA + pixIn * 2) + 1);
        fB0 = __builtin_nontemporal_load((const fv4*)(flowB + pixIn * 2));
        fB1 = __builtin_nontemporal_load((const fv4*)(flowB + pixIn * 2) + 1);
    }

#pragma unroll
    for (int i = 0; i < 4; ++i) {
        const int X0  = (txb + i) * TS;
        const int AX0 = X0 - APR;
        const int x   = X0 + lx;
        const size_t pixIn = rowBase + x;

        __syncthreads();                     // prev compute done; LDS reusable
        // Commit staged regs -> LDS (ds_write_b128, conflict-free).
#pragma unroll
        for (int k = 0; k < 10; ++k) {
            const int d = tid * 4 + k * 1024;
            if (d < NDW) {
                const int row = d / ROWD;
                const int rd  = d - row * ROWD;
                *(fv4*)(lds + row * LSTR + rd) = st[k];
            }
        }
        const fv4 a0 = fA0, a1 = fA1, c0 = fB0, c1 = fB1;  // current flows
        __syncthreads();

        // Prefetch next tile; latency hides under compute+stores below.
        if (i < 3) {
            load_stage(imgb, AX0 + TS, AY0, tid, st);
            const size_t pixInN = pixIn + TS;
            fA0 = __builtin_nontemporal_load((const fv4*)(flowA + pixInN * 2));
            fA1 = __builtin_nontemporal_load((const fv4*)(flowA + pixInN * 2) + 1);
            fB0 = __builtin_nontemporal_load((const fv4*)(flowB + pixInN * 2));
            fB1 = __builtin_nontemporal_load((const fv4*)(flowB + pixInN * 2) + 1);
        }

        float* oA = out + (opA * NPIX + pixIn) * 3;
        float* oB = out + (opB * NPIX + pixIn) * 3;

        // Op A: compute 4 samples, store immediately (shorter res live-range).
        {
            const float fly[4] = {a0.x, a0.z, a1.x, a1.z};
            const float flx[4] = {a0.y, a0.w, a1.y, a1.w};
            float res[12];
#pragma unroll
            for (int p = 0; p < 4; ++p)
                sample(imgb, lds, AX0, AY0, (float)y - fly[p], (float)(x + p) - flx[p], res + 3 * p);
            fv4 v0s = {res[0], res[1], res[2],  res[3]};
            fv4 v1s = {res[4], res[5], res[6],  res[7]};
            fv4 v2s = {res[8], res[9], res[10], res[11]};
            __builtin_nontemporal_store(v0s, (fv4*)oA);
            __builtin_nontemporal_store(v1s, (fv4*)oA + 1);
            __builtin_nontemporal_store(v2s, (fv4*)oA + 2);
        }
        // Op B
        {
            const float fly[4] = {c0.x, c0.z, c1.x, c1.z};
            const float flx[4] = {c0.y, c0.w, c1.y, c1.w};
            float res[12];
#pragma unroll
            for (int p = 0; p < 4; ++p)
                sample(imgb, lds, AX0, AY0, (float)y - fly[p], (float)(x + p) - flx[p], res + 3 * p);
            fv4 v0s = {res[0], res[1], res[2],  res[3]};
            fv4 v1s = {res[4], res[5], res[6],  res[7]};
            fv4 v2s = {res[8], res[9], res[10], res[11]};
            __builtin_nontemporal_store(v0s, (fv4*)oB);
            __builtin_nontemporal_store(v1s, (fv4*)oB + 1);
            __builtin_nontemporal_store(v2s, (fv4*)oB + 2);
        }
    }
}

extern "C" void kernel_launch(void* const* d_in, const int* in_sizes, int n_in,
                              void* d_out, int out_size, void* d_ws, size_t ws_size,
                              hipStream_t stream) {
    const float* frame0 = (const float*)d_in[0];
    const float* frame1 = (const float*)d_in[1];
    const float* f01    = (const float*)d_in[2];
    const float* f10    = (const float*)d_in[3];
    const float* ft0    = (const float*)d_in[4];
    const float* ft1    = (const float*)d_in[5];
    float* out = (float*)d_out;

    // 2 frame-groups * 16 b * 256 tiles / 4 tiles-per-block = 2048 blocks.
    hipLaunchKernelGGL(warp_pipe_kernel, dim3(2048), dim3(256), 0, stream,
                       frame0, frame1, f01, f10, ft0, ft1, out);
}

// Round 8
// 103.114 us; speedup vs baseline: 1.7706x; 1.6263x over previous
//
#include <hip/hip_runtime.h>

// (B,H,W,C) = (16,512,512,3) float32. 4 warp ops.
// out concat order: 0:(frame1,f01) 1:(frame0,f10) 2:(frame0,ft0) 3:(frame1,ft1)
#define HH 512
#define WW 512
#define NPIX (16 * HH * WW)
#define IMG_DW (HH * WW * 3)     // dwords per image
#define ROWD_G (WW * 3)          // global image row stride in dwords

#define TS    32                 // output tile edge
#define APR   12                 // apron
#define LW    (TS + 2 * APR)     // 56
#define ROWD  (LW * 3)           // 168 payload dwords per region row
#define LSTR  172                // padded LDS row stride (16B chunk-aligned: 172%4==0)
#define LDSDW (LW * LSTR)        // 9632 staged dwords (2408 16B chunks)

typedef float fv4 __attribute__((ext_vector_type(4)));
typedef float fv2 __attribute__((ext_vector_type(2)));
typedef fv4 fv4u __attribute__((aligned(4)));
typedef fv2 fv2u __attribute__((aligned(4)));

__device__ __forceinline__ void sample(const float* __restrict__ imgb,
                                       const float* __restrict__ s,
                                       int AX0, int AY0,
                                       float qy, float qx, float* __restrict__ r)
{
    float fy = floorf(qy); fy = fminf(fmaxf(fy, 0.0f), (float)(HH - 2));
    float fx = floorf(qx); fx = fminf(fmaxf(fx, 0.0f), (float)(WW - 2));
    const float ay = fminf(fmaxf(qy - fy, 0.0f), 1.0f);
    const float ax = fminf(fmaxf(qx - fx, 0.0f), 1.0f);
    const int y0 = (int)fy, x0 = (int)fx;
    const int yl = y0 - AY0, xl = x0 - AX0;
    if ((unsigned)yl < (unsigned)(LW - 1) && (unsigned)xl < (unsigned)(LW - 1)) {
        // LDS path: AoS rows; adjacent-pair dwords -> ds_read2_b32
        const float* t  = s + yl * LSTR + 3 * xl;
        const float* bo = t + LSTR;
#pragma unroll
        for (int c = 0; c < 3; ++c) {
            const float tl = t[c],  tr = t[c + 3];
            const float bl = bo[c], br = bo[c + 3];
            const float top = tl + ax * (tr - tl);
            const float bot = bl + ax * (br - bl);
            r[c] = top + ay * (bot - top);
        }
    } else {
        // rare global fallback (|flow| beyond apron): exact same math
        const float* t  = imgb + ((size_t)y0 * WW + x0) * 3;
        const float* bo = t + WW * 3;
        const fv4u t4 = *(const fv4u*)t;  const fv2u t2 = *(const fv2u*)(t + 4);
        const fv4u b4 = *(const fv4u*)bo; const fv2u b2 = *(const fv2u*)(bo + 4);
        const float tv[6] = {t4.x, t4.y, t4.z, t4.w, t2.x, t2.y};
        const float bv[6] = {b4.x, b4.y, b4.z, b4.w, b2.x, b2.y};
#pragma unroll
        for (int c = 0; c < 3; ++c) {
            const float top = tv[c] + ax * (tv[c + 3] - tv[c]);
            const float bot = bv[c] + ax * (bv[c + 3] - bv[c]);
            r[c] = top + ay * (bot - top);
        }
    }
}

__global__ __launch_bounds__(256) void warp_glds_kernel(
    const float* __restrict__ frame0, const float* __restrict__ frame1,
    const float* __restrict__ f01, const float* __restrict__ f10,
    const float* __restrict__ ft0, const float* __restrict__ ft1,
    float* __restrict__ out)
{
    __shared__ float lds[LDSDW];   // 38,528 B -> 4 blocks/CU

    // 8192 blocks; bijective XCD chunking: each XCD gets 1024 contiguous units
    // (= 4 whole (fg,b) images; 3 MB image fits 4 MB per-XCD L2).
    const unsigned bid = blockIdx.x;
    const unsigned v   = (bid & 7u) * 1024u + (bid >> 3);

    const unsigned tile  = v & 255u;   // 16x16 tiles per image
    const unsigned img_b = v >> 8;     // 0..31
    const int b  = (int)(img_b & 15u);
    const int fg = (int)(img_b >> 4);  // 0: frame0 ops{1,2}, 1: frame1 ops{0,3}

    const int tx = (int)(tile & 15u);
    const int ty = (int)(tile >> 4);
    const int X0 = tx * TS, Y0 = ty * TS;
    const int AX0 = X0 - APR, AY0 = Y0 - APR;

    const float* img   = fg ? frame1 : frame0;
    const float* flowA = fg ? f01 : f10;
    const float* flowB = fg ? ft1 : ft0;
    const size_t opA   = fg ? 0 : 1;
    const size_t opB   = fg ? 3 : 2;

    const float* imgb = img + (size_t)b * IMG_DW;

    const int tid = (int)threadIdx.x;
    const int lx = (tid & 7) * 4;      // 8 threads x 4 px cover 32 px row
    const int ly = tid >> 3;           // 32 rows
    const int x = X0 + lx, y = Y0 + ly;
    const size_t pixIn = ((size_t)b * HH + y) * WW + x;

    // Flow loads into regs; consumed after the barrier (waits fold into it).
    const fv4 a0 = __builtin_nontemporal_load((const fv4*)(flowA + pixIn * 2));
    const fv4 a1 = __builtin_nontemporal_load((const fv4*)(flowA + pixIn * 2) + 1);
    const fv4 c0 = __builtin_nontemporal_load((const fv4*)(flowB + pixIn * 2));
    const fv4 c1 = __builtin_nontemporal_load((const fv4*)(flowB + pixIn * 2) + 1);

    // ---- Stage apron region HBM -> LDS via global_load_lds (async, 0 VGPR).
    // 2408 16B chunks; thread tid handles chunk c = it*256+tid. LDS dest is
    // wave-uniform base + lane*16 (HW contract); 172%4==0 so each chunk is
    // pure payload or the pure pad chunk (rd==168, loads garbage, never read).
    // Out-of-image apron cells are never read (bilinear clip), so the source
    // index only needs clamping for fault-safety, not correctness.
    {
        const unsigned wid = __builtin_amdgcn_readfirstlane((unsigned)tid >> 6);
        int D   = tid * 4;             // LDS dword index of this thread's chunk
        int row = D / LSTR;            // magic-mul, once
        int rd  = D - row * LSTR;
#pragma unroll
        for (int it = 0; it < 10; ++it) {
            if (tid * 4 + it * 1024 < LDSDW) {     // it<9: always true
                const int gy = min(max(AY0 + row, 0), HH - 1);
                int idx = gy * ROWD_G + AX0 * 3 + rd;
                idx = min(max(idx, 0), IMG_DW - 4);
                const float* src = imgb + idx;
                float* dst = (float*)lds + it * 1024 + wid * 256;
                __builtin_amdgcn_global_load_lds(
                    (const __attribute__((address_space(1))) void*)src,
                    (__attribute__((address_space(3))) void*)dst, 16, 0, 0);
            }
            // advance D by 1024: 1024 = 5*172 + 164
            row += 5; rd += 164;
            if (rd >= LSTR) { rd -= LSTR; ++row; }
        }
    }
    __syncthreads();   // compiler drains vmcnt before s_barrier

    float* oA = out + (opA * NPIX + pixIn) * 3;
    float* oB = out + (opB * NPIX + pixIn) * 3;

    // Op A: compute 4 samples, store immediately (short res live-range).
    {
        const float fly[4] = {a0.x, a0.z, a1.x, a1.z};
        const float flx[4] = {a0.y, a0.w, a1.y, a1.w};
        float res[12];
#pragma unroll
        for (int p = 0; p < 4; ++p)
            sample(imgb, lds, AX0, AY0, (float)y - fly[p], (float)(x + p) - flx[p], res + 3 * p);
        fv4 v0s = {res[0], res[1], res[2],  res[3]};
        fv4 v1s = {res[4], res[5], res[6],  res[7]};
        fv4 v2s = {res[8], res[9], res[10], res[11]};
        __builtin_nontemporal_store(v0s, (fv4*)oA);
        __builtin_nontemporal_store(v1s, (fv4*)oA + 1);
        __builtin_nontemporal_store(v2s, (fv4*)oA + 2);
    }
    // Op B
    {
        const float fly[4] = {c0.x, c0.z, c1.x, c1.z};
        const float flx[4] = {c0.y, c0.w, c1.y, c1.w};
        float res[12];
#pragma unroll
        for (int p = 0; p < 4; ++p)
            sample(imgb, lds, AX0, AY0, (float)y - fly[p], (float)(x + p) - flx[p], res + 3 * p);
        fv4 v0s = {res[0], res[1], res[2],  res[3]};
        fv4 v1s = {res[4], res[5], res[6],  res[7]};
        fv4 v2s = {res[8], res[9], res[10], res[11]};
        __builtin_nontemporal_store(v0s, (fv4*)oB);
        __builtin_nontemporal_store(v1s, (fv4*)oB + 1);
        __builtin_nontemporal_store(v2s, (fv4*)oB + 2);
    }
}

extern "C" void kernel_launch(void* const* d_in, const int* in_sizes, int n_in,
                              void* d_out, int out_size, void* d_ws, size_t ws_size,
                              hipStream_t stream) {
    const float* frame0 = (const float*)d_in[0];
    const float* frame1 = (const float*)d_in[1];
    const float* f01    = (const float*)d_in[2];
    const float* f10    = (const float*)d_in[3];
    const float* ft0    = (const float*)d_in[4];
    const float* ft1    = (const float*)d_in[5];
    float* out = (float*)d_out;

    // 2 frame-groups * 16 b * 256 tiles = 8192 blocks of 256 threads.
    hipLaunchKernelGGL(warp_glds_kernel, dim3(8192), dim3(256), 0, stream,
                       frame0, frame1, f01, f10, ft0, ft1, out);
}

// Round 9
// 94.722 us; speedup vs baseline: 1.9275x; 1.0886x over previous
//
#include <hip/hip_runtime.h>

// (B,H,W,C) = (16,512,512,3) float32. 4 warp ops.
// out concat order: 0:(frame1,f01) 1:(frame0,f10) 2:(frame0,ft0) 3:(frame1,ft1)
#define HH 512
#define WW 512
#define NPIX (16 * HH * WW)
#define IMG_DW (HH * WW * 3)     // dwords per image
#define ROWD_G (WW * 3)          // global image row stride in dwords

#define TSX   32                 // output tile width
#define TSY   16                 // output tile height
#define APR   12                 // apron
#define LWX   (TSX + 2 * APR)    // 56: staged region width (px)
#define LWY   (TSY + 2 * APR)    // 40: staged region height (rows)
#define ROWD  (LWX * 3)          // 168 payload dwords per region row
#define LSTR  172                // padded LDS row stride (16B chunk-aligned: 172%4==0)
#define LDSDW (LWY * LSTR)       // 6880 dwords = 27,520 B -> 5 blocks/CU

typedef float fv4 __attribute__((ext_vector_type(4)));
typedef float fv2 __attribute__((ext_vector_type(2)));
typedef fv4 fv4u __attribute__((aligned(4)));
typedef fv2 fv2u __attribute__((aligned(4)));

__device__ __forceinline__ void sample(const float* __restrict__ imgb,
                                       const float* __restrict__ s,
                                       int AX0, int AY0,
                                       float qy, float qx, float* __restrict__ r)
{
    float fy = floorf(qy); fy = fminf(fmaxf(fy, 0.0f), (float)(HH - 2));
    float fx = floorf(qx); fx = fminf(fmaxf(fx, 0.0f), (float)(WW - 2));
    const float ay = fminf(fmaxf(qy - fy, 0.0f), 1.0f);
    const float ax = fminf(fmaxf(qx - fx, 0.0f), 1.0f);
    const int y0 = (int)fy, x0 = (int)fx;
    const int yl = y0 - AY0, xl = x0 - AX0;
    if ((unsigned)yl < (unsigned)(LWY - 1) && (unsigned)xl < (unsigned)(LWX - 1)) {
        // LDS path: AoS rows; adjacent-pair dwords -> ds_read2_b32
        const float* t  = s + yl * LSTR + 3 * xl;
        const float* bo = t + LSTR;
#pragma unroll
        for (int c = 0; c < 3; ++c) {
            const float tl = t[c],  tr = t[c + 3];
            const float bl = bo[c], br = bo[c + 3];
            const float top = tl + ax * (tr - tl);
            const float bot = bl + ax * (br - bl);
            r[c] = top + ay * (bot - top);
        }
    } else {
        // rare global fallback (|flow| beyond apron): exact same math
        const float* t  = imgb + ((size_t)y0 * WW + x0) * 3;
        const float* bo = t + WW * 3;
        const fv4u t4 = *(const fv4u*)t;  const fv2u t2 = *(const fv2u*)(t + 4);
        const fv4u b4 = *(const fv4u*)bo; const fv2u b2 = *(const fv2u*)(bo + 4);
        const float tv[6] = {t4.x, t4.y, t4.z, t4.w, t2.x, t2.y};
        const float bv[6] = {b4.x, b4.y, b4.z, b4.w, b2.x, b2.y};
#pragma unroll
        for (int c = 0; c < 3; ++c) {
            const float top = tv[c] + ax * (tv[c + 3] - tv[c]);
            const float bot = bv[c] + ax * (bv[c + 3] - bv[c]);
            r[c] = top + ay * (bot - top);
        }
    }
}

__global__ __launch_bounds__(256) void warp_glds16_kernel(
    const float* __restrict__ frame0, const float* __restrict__ frame1,
    const float* __restrict__ f01, const float* __restrict__ f10,
    const float* __restrict__ ft0, const float* __restrict__ ft1,
    float* __restrict__ out)
{
    __shared__ float lds[LDSDW];   // 27,520 B -> 5 blocks/CU (20 waves, 62.5%)

    // 16384 blocks; bijective XCD chunking: XCD k gets 2048 contiguous units
    // = 4 whole (fg,b) images; consecutive units walk one image row-by-row,
    // so apron re-reads between y-adjacent tile rows stay L2-resident.
    const unsigned bid = blockIdx.x;
    const unsigned v   = (bid & 7u) * 2048u + (bid >> 3);

    const unsigned tile  = v & 511u;   // 16 x 32 tiles per image
    const unsigned img_b = v >> 9;     // 0..31
    const int b  = (int)(img_b & 15u);
    const int fg = (int)(img_b >> 4);  // 0: frame0 ops{1,2}, 1: frame1 ops{0,3}

    const int tx = (int)(tile & 15u);
    const int ty = (int)(tile >> 4);
    const int X0 = tx * TSX, Y0 = ty * TSY;
    const int AX0 = X0 - APR, AY0 = Y0 - APR;

    const float* img   = fg ? frame1 : frame0;
    const float* flowA = fg ? f01 : f10;
    const float* flowB = fg ? ft1 : ft0;
    const size_t opA   = fg ? 0 : 1;
    const size_t opB   = fg ? 3 : 2;

    const float* imgb = img + (size_t)b * IMG_DW;

    const int tid = (int)threadIdx.x;
    const int lx = (tid & 15) * 2;     // 16 threads x 2 px cover 32 px row
    const int ly = tid >> 4;           // 16 rows
    const int x = X0 + lx, y = Y0 + ly;
    const size_t pixIn = ((size_t)b * HH + y) * WW + x;

    // Flow loads (2 px -> one 16B load per op); consumed after the barrier.
    const fv4 a = __builtin_nontemporal_load((const fv4*)(flowA + pixIn * 2));
    const fv4 c = __builtin_nontemporal_load((const fv4*)(flowB + pixIn * 2));

    // ---- Stage apron region HBM -> LDS via global_load_lds (async, 0 VGPR).
    // 1720 16B chunks; thread tid handles chunk it*256+tid. LDS dest is
    // wave-uniform base + lane*16 (HW contract); 172%4==0 so each chunk is
    // pure payload or the pure pad chunk (rd==168, loads garbage, never read).
    // Out-of-image apron cells are never read (bilinear clip); source index
    // clamp is fault-safety only.
    {
        const unsigned wid = __builtin_amdgcn_readfirstlane((unsigned)tid >> 6);
        int D   = tid * 4;             // LDS dword index of this thread's chunk
        int row = D / LSTR;            // magic-mul, once
        int rd  = D - row * LSTR;
#pragma unroll
        for (int it = 0; it < 7; ++it) {
            if (it < 6 || tid < 184) { // 1720 - 6*256 = 184 tail chunks
                const int gy = min(max(AY0 + row, 0), HH - 1);
                int idx = gy * ROWD_G + AX0 * 3 + rd;
                idx = min(max(idx, 0), IMG_DW - 4);
                const float* src = imgb + idx;
                float* dst = (float*)lds + it * 1024 + wid * 256;
                __builtin_amdgcn_global_load_lds(
                    (const __attribute__((address_space(1))) void*)src,
                    (__attribute__((address_space(3))) void*)dst, 16, 0, 0);
            }
            // advance D by 1024 dwords: 1024 = 5*172 + 164
            row += 5; rd += 164;
            if (rd >= LSTR) { rd -= LSTR; ++row; }
        }
    }
    __syncthreads();   // compiler drains vmcnt before s_barrier

    float* oA = out + (opA * NPIX + pixIn) * 3;
    float* oB = out + (opB * NPIX + pixIn) * 3;

    // Op A: 2 samples, store immediately (short live-range).
    {
        float res[6];
        sample(imgb, lds, AX0, AY0, (float)y - a.x, (float)x       - a.y, res);
        sample(imgb, lds, AX0, AY0, (float)y - a.z, (float)(x + 1) - a.w, res + 3);
        fv2 v0s = {res[0], res[1]};
        fv2 v1s = {res[2], res[3]};
        fv2 v2s = {res[4], res[5]};
        __builtin_nontemporal_store(v0s, (fv2*)oA);
        __builtin_nontemporal_store(v1s, (fv2*)oA + 1);
        __builtin_nontemporal_store(v2s, (fv2*)oA + 2);
    }
    // Op B
    {
        float res[6];
        sample(imgb, lds, AX0, AY0, (float)y - c.x, (float)x       - c.y, res);
        sample(imgb, lds, AX0, AY0, (float)y - c.z, (float)(x + 1) - c.w, res + 3);
        fv2 v0s = {res[0], res[1]};
        fv2 v1s = {res[2], res[3]};
        fv2 v2s = {res[4], res[5]};
        __builtin_nontemporal_store(v0s, (fv2*)oB);
        __builtin_nontemporal_store(v1s, (fv2*)oB + 1);
        __builtin_nontemporal_store(v2s, (fv2*)oB + 2);
    }
}

extern "C" void kernel_launch(void* const* d_in, const int* in_sizes, int n_in,
                              void* d_out, int out_size, void* d_ws, size_t ws_size,
                              hipStream_t stream) {
    const float* frame0 = (const float*)d_in[0];
    const float* frame1 = (const float*)d_in[1];
    const float* f01    = (const float*)d_in[2];
    const float* f10    = (const float*)d_in[3];
    const float* ft0    = (const float*)d_in[4];
    const float* ft1    = (const float*)d_in[5];
    float* out = (float*)d_out;

    // 2 frame-groups * 16 b * 512 tiles = 16384 blocks of 256 threads.
    hipLaunchKernelGGL(warp_glds16_kernel, dim3(16384), dim3(256), 0, stream,
                       frame0, frame1, f01, f10, ft0, ft1, out);
}